// Round 3
// baseline (89.361 us; speedup 1.0000x reference)
//
#include <hip/hip_runtime.h>

typedef __attribute__((ext_vector_type(8))) short bf16x8;
typedef __attribute__((ext_vector_type(4))) float f32x4;

#define EPSV 1e-5f
// (1/TEMP) * log2(e),  TEMP = 0.5  -> exp2-domain scale
#define SCALE 2.885390081777927f

#if __has_builtin(__builtin_amdgcn_exp2f)
__device__ __forceinline__ float fast_exp2(float x) { return __builtin_amdgcn_exp2f(x); }
#else
__device__ __forceinline__ float fast_exp2(float x) {
  float r; asm("v_exp_f32 %0, %1" : "=v"(r) : "v"(x)); return r;
}
#endif

__device__ __forceinline__ ushort f32_to_bf16(float f) {
  union { float f; unsigned u; } cv; cv.f = f;
  unsigned u = cv.u;
  u += 0x7FFFu + ((u >> 16) & 1u);   // round-to-nearest-even
  return (ushort)(u >> 16);
}

// ---------------------------------------------------------------------------
// Fused prep kernel, grid = 512 + 512 + 64 = 1088 blocks, 256 threads.
//  [0,512):   pack anchors  [B,C,H,W] f32 -> Apk[p][n][c] bf16 (coalesced via
//             LDS transpose) + pos-pair dot posDot[p*64+n] (f32)
//  [512,1024): per-patch label mean -> flags
//  [1024,1088): bank repack [L,C,8,8] f32 -> [2048][256] bf16, pre-scaled
// ---------------------------------------------------------------------------
__global__ __launch_bounds__(256) void cpl_prep(
    const float* __restrict__ mainO, const float* __restrict__ emaO,
    const float* __restrict__ label, const float* __restrict__ negB,
    const float* __restrict__ posB,
    ushort* __restrict__ Apk, float* __restrict__ posDot,
    int* __restrict__ flags, ushort* __restrict__ bankN, ushort* __restrict__ bankP)
{
  __shared__ ushort shU[64 * 256];   // 32 KiB
  __shared__ float  shF[4][64];
  const int bid = blockIdx.x;
  const int t = threadIdx.x;

  if (bid < 512) {
    // ---- anchor pack + pos dot: block = (b, y) ----
    const int b = bid >> 6, y = bid & 63;
    const int cg = t >> 4;            // c-offset 0..15
    const int x4 = t & 15;            // float4 index along W
    const float* mB = mainO + (((size_t)b * 256 + cg) * 64 + y) * 64 + x4 * 4;
    const float* eB = emaO  + (((size_t)b * 256 + cg) * 64 + y) * 64 + x4 * 4;
    float4 acc4 = make_float4(0.f, 0.f, 0.f, 0.f);
#pragma unroll
    for (int pass = 0; pass < 16; ++pass) {
      const int c = pass * 16 + cg;
      const float4 mv = *(const float4*)(mB + (size_t)pass * 16 * 4096);
      const float4 ev = *(const float4*)(eB + (size_t)pass * 16 * 4096);
      acc4.x += mv.x * ev.x; acc4.y += mv.y * ev.y;
      acc4.z += mv.z * ev.z; acc4.w += mv.w * ev.w;
      const float vals[4] = {mv.x, mv.y, mv.z, mv.w};
#pragma unroll
      for (int j = 0; j < 4; ++j) {
        const int x = x4 * 4 + j;
        shU[x * 256 + (c ^ ((x & 7) << 3))] = f32_to_bf16(vals[j]);
      }
    }
    // reduce pos partials over c-groups (cg bit0 = lane bit4, bit1 = lane bit5)
    acc4.x += __shfl_xor(acc4.x, 16, 64); acc4.y += __shfl_xor(acc4.y, 16, 64);
    acc4.z += __shfl_xor(acc4.z, 16, 64); acc4.w += __shfl_xor(acc4.w, 16, 64);
    acc4.x += __shfl_xor(acc4.x, 32, 64); acc4.y += __shfl_xor(acc4.y, 32, 64);
    acc4.z += __shfl_xor(acc4.z, 32, 64); acc4.w += __shfl_xor(acc4.w, 32, 64);
    if ((t & 63) < 16) *(float4*)&shF[t >> 6][(t & 15) * 4] = acc4;
    __syncthreads();
    // write packed anchors (coalesced b128)
#pragma unroll
    for (int it = 0; it < 8; ++it) {
      const int lin = it * 256 + t;          // 0..2047
      const int x = lin >> 5, c8 = lin & 31;
      const uint4 v = *(const uint4*)&shU[x * 256 + ((c8 * 8) ^ ((x & 7) << 3))];
      const int p = b * 64 + ((y >> 3) << 3) + (x >> 3);
      const int n = ((y & 7) << 3) + (x & 7);
      *(uint4*)&Apk[((size_t)p * 64 + n) * 256 + c8 * 8] = v;
    }
    if (t < 64) {
      const float pv = shF[0][t] + shF[1][t] + shF[2][t] + shF[3][t];
      const int p = b * 64 + ((y >> 3) << 3) + (t >> 3);
      const int n = ((y & 7) << 3) + (t & 7);
      posDot[p * 64 + n] = pv;
    }
  } else if (bid < 1024) {
    // ---- label mean -> flag ----
    const int p = bid - 512;
    const int b = p >> 6, pj = (p >> 3) & 7, pk = p & 7;
    const size_t base = ((size_t)b * 256 + pj * 32) * 256 + pk * 32;
    float s = 0.f;
#pragma unroll
    for (int i = 0; i < 4; ++i) {
      const int e = t * 4 + i;               // 0..1023, r=e>>5, cc=e&31
      s += label[base + (size_t)(e >> 5) * 256 + (e & 31)];
    }
#pragma unroll
    for (int d = 1; d < 64; d <<= 1) s += __shfl_xor(s, d, 64);
    if ((t & 63) == 0) shF[0][t >> 6] = s;
    __syncthreads();
    if (t == 0)
      flags[p] = ((shF[0][0] + shF[0][1] + shF[0][2] + shF[0][3]) * (1.f / 1024.f) < 0.1f) ? 1 : 0;
  } else {
    // ---- bank repack (pre-scaled by SCALE) ----
    const int bb = bid - 1024;
    const float* src = (bb < 32 ? negB : posB) + (size_t)(bb & 31) * 16384;
    ushort* dst = (bb < 32 ? bankN : bankP) + (size_t)(bb & 31) * 64 * 256;
#pragma unroll 8
    for (int it = 0; it < 64; ++it) {
      const int lin = it * 256 + t;          // [c][posi] linear, coalesced read
      const int c = lin >> 6, posi = lin & 63;
      shU[(posi * 256 + c) ^ ((posi & 31) << 1)] = f32_to_bf16(src[lin] * SCALE);
    }
    __syncthreads();
    unsigned* dst32 = (unsigned*)dst;
#pragma unroll 8
    for (int it = 0; it < 32; ++it) {
      const int lin = it * 256 + t;          // uint index: 128 uints per row
      const int posi = lin >> 7, c = (lin & 127) << 1;
      const int idx = (posi * 256 + c) ^ ((posi & 31) << 1);
      dst32[lin] = *(const unsigned*)&shU[idx];
    }
  }
}

// ---------------------------------------------------------------------------
// Main kernel: grid=512 (one patch each), block=256 (4 waves).
// A fragments pinned in registers; B streamed from L2 with a deferred-exp2
// software pipeline: issue loads(nt) -> exp2(acc of nt-1) -> MFMA(nt).
// Per-row -pos shift read from LDS at tile init (saves 16 VGPRs).
// ---------------------------------------------------------------------------
__global__ __launch_bounds__(256, 2) void cpl_main(
    const ushort* __restrict__ Apk, const float* __restrict__ posDot,
    const ushort* __restrict__ bankN, const ushort* __restrict__ bankP,
    const int* __restrict__ flags, float* __restrict__ blockSums)
{
  __shared__ float posNeg[64];
  __shared__ float swS[4][64];

  const int p = blockIdx.x;
  const int t = threadIdx.x;
  if (t < 64) posNeg[t] = -posDot[p * 64 + t] * SCALE;
  __syncthreads();

  const int l = t & 63, w = t >> 6;
  const int r16 = l & 15, kg = l >> 4;

  // ---- A fragments: lane l holds A[mt*16+(l&15)][ks*32+(l>>4)*8 + 0..7] ----
  const ushort* Ab = Apk + (size_t)p * 16384;
  bf16x8 afrag[4][8];
#pragma unroll
  for (int mt = 0; mt < 4; ++mt)
#pragma unroll
    for (int ks = 0; ks < 8; ++ks)
      afrag[mt][ks] = *(const bf16x8*)(Ab + (mt * 16 + r16) * 256 + ks * 32 + kg * 8);
#pragma unroll
  for (int mt = 0; mt < 4; ++mt)
#pragma unroll
    for (int ks = 0; ks < 8; ++ks)
      asm volatile("" : "+v"(afrag[mt][ks]));

  const ushort* bank = (flags[p] ? bankP : bankN);
  // wave w covers columns [w*512,(w+1)*512); lane covers col w*512 + nt*16 + r16
  const ushort* bptr0 = bank + (size_t)(w * 512 + r16) * 256 + kg * 8;

  float s[16];
#pragma unroll
  for (int e = 0; e < 16; ++e) s[e] = 0.f;

  bf16x8 bfrag[8];
  f32x4 accA[4], accB[4];

#define LOADB(NT) do { const ushort* bp_ = bptr0 + (size_t)(NT) * 4096;            \
    _Pragma("unroll") for (int ks = 0; ks < 8; ++ks)                               \
      bfrag[ks] = *(const bf16x8*)(bp_ + ks * 32); } while (0)

#define MFMA_TILE(ACC) do {                                                        \
    _Pragma("unroll") for (int mt = 0; mt < 4; ++mt)                               \
      ACC[mt] = *(const f32x4*)&posNeg[mt * 16 + kg * 4];                          \
    _Pragma("unroll") for (int ks = 0; ks < 8; ++ks)                               \
      _Pragma("unroll") for (int mt = 0; mt < 4; ++mt)                             \
        ACC[mt] = __builtin_amdgcn_mfma_f32_16x16x32_bf16(afrag[mt][ks], bfrag[ks],\
                                                          ACC[mt], 0, 0, 0);       \
  } while (0)

#define EXPACC(ACC) do {                                                           \
    _Pragma("unroll") for (int mt = 0; mt < 4; ++mt)                               \
      _Pragma("unroll") for (int i = 0; i < 4; ++i)                                \
        s[mt * 4 + i] += fast_exp2(ACC[mt][i]); } while (0)

  LOADB(0);
  MFMA_TILE(accA);
  for (int nt = 1; nt < 30; nt += 2) {
    LOADB(nt);
    EXPACC(accA);          // exp2 of tile nt-1 hides L2 latency of tile nt
    MFMA_TILE(accB);
    LOADB(nt + 1);
    EXPACC(accB);
    MFMA_TILE(accA);
  }
  LOADB(31);
  EXPACC(accA);            // tile 30
  MFMA_TILE(accB);
  EXPACC(accB);            // tile 31

#undef LOADB
#undef MFMA_TILE
#undef EXPACC

  // ---- sum the 16 column-partials (lanes differing in low 4 bits) ----
#pragma unroll
  for (int d = 1; d < 16; d <<= 1)
#pragma unroll
    for (int e = 0; e < 16; ++e) s[e] += __shfl_xor(s[e], d, 64);
  if (r16 == 0) {
#pragma unroll
    for (int mt = 0; mt < 4; ++mt)
#pragma unroll
      for (int i = 0; i < 4; ++i)
        swS[w][mt * 16 + kg * 4 + i] = s[mt * 4 + i];
  }
  __syncthreads();

  // ---- final per-row loss + block reduce (wave 0 only) ----
  if (t < 64) {
    const float S = 1.f + swS[0][t] + swS[1][t] + swS[2][t] + swS[3][t];
    float loss = -logf(1.f / S + EPSV);
#pragma unroll
    for (int d = 1; d < 64; d <<= 1) loss += __shfl_xor(loss, d, 64);
    if (t == 0) blockSums[p] = loss;
  }
}

// ---------------------------------------------------------------------------
// Final: mean of 512 block sums / (512*64).  grid=1, block=256.
// ---------------------------------------------------------------------------
__global__ void cpl_final(const float* __restrict__ blockSums, float* __restrict__ out) {
  const int t = threadIdx.x;
  float s = blockSums[t] + blockSums[t + 256];
#pragma unroll
  for (int d = 1; d < 64; d <<= 1) s += __shfl_xor(s, d, 64);
  __shared__ float ps[4];
  if ((t & 63) == 0) ps[t >> 6] = s;
  __syncthreads();
  if (t == 0) out[0] = (ps[0] + ps[1] + ps[2] + ps[3]) * (1.f / 32768.f);
}

extern "C" void kernel_launch(void* const* d_in, const int* in_sizes, int n_in,
                              void* d_out, int out_size, void* d_ws, size_t ws_size,
                              hipStream_t stream) {
  const float* mainO = (const float*)d_in[0];
  const float* emaO  = (const float*)d_in[1];
  const float* label = (const float*)d_in[2];
  const float* negB  = (const float*)d_in[3];
  const float* posB  = (const float*)d_in[4];
  float* out = (float*)d_out;

  char* ws = (char*)d_ws;
  float*  blockSums = (float*)ws;                        // 2 KiB
  int*    flags     = (int*)(ws + 2048);                 // 2 KiB
  ushort* bankN     = (ushort*)(ws + 4096);              // 1 MiB
  ushort* bankP     = (ushort*)(ws + 4096 + 1048576);    // 1 MiB
  float*  posDot    = (float*)(ws + 4096 + 2097152);     // 128 KiB
  ushort* Apk       = (ushort*)(ws + 4096 + 2097152 + 131072);  // 16.78 MiB

  hipLaunchKernelGGL(cpl_prep, dim3(1088), dim3(256), 0, stream,
                     mainO, emaO, label, negB, posB, Apk, posDot, flags, bankN, bankP);
  hipLaunchKernelGGL(cpl_main, dim3(512), dim3(256), 0, stream,
                     Apk, posDot, bankN, bankP, flags, blockSums);
  hipLaunchKernelGGL(cpl_final, dim3(1), dim3(256), 0, stream, blockSums, out);
}